// Round 2
// baseline (8310.486 us; speedup 1.0000x reference)
//
#include <hip/hip_runtime.h>
#include <cstdint>
#include <cstddef>

// Problem constants
// B=2, S=2048, D=1024, H=16, Dh=64, M = B*S = 4096
// ALL inputs/outputs are fp32 (reference dtype). Output = out (4096x1024) ++ attn (2,16,2048,2048).
#define SEQ 2048
#define DM 1024
#define NH 16
#define DH 64
#define MROWS 4096
#define LOG2_THETA 13.287712379549609f /* log2(10000) */

// ---------------------------------------------------------------------------
// Kernel 1: QKV projection + bias + RoPE (q,k), write fp32 to ws in (B,H,S,Dh)
// C(4096x1024) = x(4096x1024) @ W(1024x1024) + b
// blockIdx.z: 0=q, 1=k, 2=v. Tiled 64x64, BK=16, 16x16 threads, 4x4 microtile.
// ---------------------------------------------------------------------------
__global__ __launch_bounds__(256) void k_qkv(
    const float* __restrict__ x,
    const float* __restrict__ wq, const float* __restrict__ bq,
    const float* __restrict__ wk, const float* __restrict__ bk,
    const float* __restrict__ wv, const float* __restrict__ bv,
    float* __restrict__ qkv_ws)
{
    const int z = blockIdx.z;
    const float* W    = (z == 0) ? wq : (z == 1) ? wk : wv;
    const float* bias = (z == 0) ? bq : (z == 1) ? bk : bv;
    float* dst = qkv_ws + (size_t)z * (size_t)MROWS * DM;

    __shared__ float As[16][65];   // [k][m], padded
    __shared__ float Bs[16][64];   // [k][n]

    const int tx = threadIdx.x, ty = threadIdx.y;
    const int tid = ty * 16 + tx;
    const int row0 = blockIdx.y * 64;
    const int col0 = blockIdx.x * 64;

    float c[4][4] = {};

    for (int k0 = 0; k0 < DM; k0 += 16) {
        // A tile: 64 rows x 16 k
        {
            const int r = tid >> 4;      // 0..15
            const int kk = tid & 15;
            #pragma unroll
            for (int it = 0; it < 4; ++it) {
                const int rr = r + it * 16;
                As[kk][rr] = x[(size_t)(row0 + rr) * DM + k0 + kk];
            }
        }
        // B tile: 16 k x 64 n
        {
            const int kb = tid >> 6;     // 0..3
            const int n  = tid & 63;
            #pragma unroll
            for (int it = 0; it < 4; ++it) {
                const int kr = kb + it * 4;
                Bs[kr][n] = W[(size_t)(k0 + kr) * DM + col0 + n];
            }
        }
        __syncthreads();
        #pragma unroll
        for (int kk = 0; kk < 16; ++kk) {
            float a[4], b[4];
            #pragma unroll
            for (int i = 0; i < 4; ++i) a[i] = As[kk][ty * 4 + i];
            #pragma unroll
            for (int j = 0; j < 4; ++j) b[j] = Bs[kk][tx * 4 + j];
            #pragma unroll
            for (int i = 0; i < 4; ++i)
                #pragma unroll
                for (int j = 0; j < 4; ++j)
                    c[i][j] += a[i] * b[j];
        }
        __syncthreads();
    }

    // Epilogue: bias (+RoPE for q,k), store fp32 to (B,H,S,Dh)
    #pragma unroll
    for (int i = 0; i < 4; ++i) {
        const int m = row0 + ty * 4 + i;
        const int s = m & (SEQ - 1);
        const int bb = m >> 11;
        if (z < 2) {
            #pragma unroll
            for (int j = 0; j < 4; j += 2) {
                const int n = col0 + tx * 4 + j;       // even column
                const int d = n & (DH - 1);
                const int h = (n >> 6) & (NH - 1);
                const float freq = exp2f((float)d * (-LOG2_THETA / 64.0f));
                const float ang = (float)s * freq;
                float sn, cs;
                sincosf(ang, &sn, &cs);
                const float e = c[i][j]     + bias[n];
                const float o = c[i][j + 1] + bias[n + 1];
                float* dp = &dst[((size_t)(bb * NH + h) * SEQ + s) * DH + d];
                dp[0] = e * cs - o * sn;
                dp[1] = e * sn + o * cs;
            }
        } else {
            #pragma unroll
            for (int j = 0; j < 4; ++j) {
                const int n = col0 + tx * 4 + j;
                const int d = n & (DH - 1);
                const int h = (n >> 6) & (NH - 1);
                dst[((size_t)(bb * NH + h) * SEQ + s) * DH + d] = c[i][j] + bias[n];
            }
        }
    }
}

// ---------------------------------------------------------------------------
// Kernel 2: attention for one (b,h), 4 query rows per block.
// scores (4x2048) in LDS -> softmax (wave-wide, row==wave) -> write attn fp32
// -> PV into head_out fp32 at (B,S,H*Dh).
// ---------------------------------------------------------------------------
__global__ __launch_bounds__(256) void k_attn(
    const float* __restrict__ qkv_ws,
    float* __restrict__ attn_out,
    float* __restrict__ ho)
{
    __shared__ float sQ[4][64];
    __shared__ float sS[4][SEQ];
    __shared__ float sK[64][65];

    const int b = blockIdx.z, h = blockIdx.y;
    const int q0 = blockIdx.x * 4;
    const size_t bh = (size_t)(b * NH + h);
    const float* Q = qkv_ws + bh * SEQ * DH;
    const float* K = Q + (size_t)MROWS * DM;        // +4194304 floats
    const float* V = Q + 2ull * MROWS * DM;

    const int tid = threadIdx.x;
    const int g = tid >> 6;   // row within tile, == wave id
    const int l = tid & 63;   // lane

    sQ[g][l] = Q[(size_t)(q0 + g) * DH + l];
    __syncthreads();

    // --- scores ---
    for (int kb = 0; kb < SEQ / 64; ++kb) {
        #pragma unroll
        for (int it = 0; it < 16; ++it) {
            const int idx = tid + it * 256;
            const int kj = idx >> 6, d = idx & 63;
            sK[kj][d] = K[(size_t)(kb * 64 + kj) * DH + d];
        }
        __syncthreads();
        float s = 0.f;
        #pragma unroll
        for (int d = 0; d < 64; ++d) s += sQ[g][d] * sK[l][d];
        sS[g][kb * 64 + l] = s * 0.125f;
        __syncthreads();
    }

    // --- softmax (row g handled by wave g; lane l covers k = j*64+l) ---
    float mx = -1e30f;
    #pragma unroll
    for (int j = 0; j < 32; ++j) mx = fmaxf(mx, sS[g][j * 64 + l]);
    #pragma unroll
    for (int off = 32; off >= 1; off >>= 1) mx = fmaxf(mx, __shfl_xor(mx, off));

    float p[32];
    float sum = 0.f;
    #pragma unroll
    for (int j = 0; j < 32; ++j) { p[j] = expf(sS[g][j * 64 + l] - mx); sum += p[j]; }
    #pragma unroll
    for (int off = 32; off >= 1; off >>= 1) sum += __shfl_xor(sum, off);
    const float inv = 1.f / sum;

    const size_t arow = (bh * SEQ + (size_t)(q0 + g)) * SEQ;
    #pragma unroll
    for (int j = 0; j < 32; ++j) {
        const float pn = p[j] * inv;
        sS[g][j * 64 + l] = pn;
        attn_out[arow + j * 64 + l] = pn;
    }
    __syncthreads();

    // --- PV: out[g][l] = sum_k P[g][k] * V[k][l] ---
    float acc = 0.f;
    for (int kb = 0; kb < SEQ / 64; ++kb) {
        #pragma unroll
        for (int it = 0; it < 16; ++it) {
            const int idx = tid + it * 256;
            const int kj = idx >> 6, d = idx & 63;
            sK[kj][d] = V[(size_t)(kb * 64 + kj) * DH + d];
        }
        __syncthreads();
        #pragma unroll
        for (int j = 0; j < 64; ++j) acc += sS[g][kb * 64 + j] * sK[j][l];
        __syncthreads();
    }
    // head_out in (B,S,H,Dh) flattened = (4096 x 1024) with col = h*64+d
    ho[((size_t)(b * SEQ + q0 + g) * NH + h) * DH + l] = acc;
}

// ---------------------------------------------------------------------------
// Kernel 3: out = ho(4096x1024,fp32) @ wo + bo -> fp32
// ---------------------------------------------------------------------------
__global__ __launch_bounds__(256) void k_oproj(
    const float* __restrict__ ho,
    const float* __restrict__ wo, const float* __restrict__ bo,
    float* __restrict__ out)
{
    __shared__ float As[16][65];
    __shared__ float Bs[16][64];

    const int tx = threadIdx.x, ty = threadIdx.y;
    const int tid = ty * 16 + tx;
    const int row0 = blockIdx.y * 64;
    const int col0 = blockIdx.x * 64;

    float c[4][4] = {};

    for (int k0 = 0; k0 < DM; k0 += 16) {
        {
            const int r = tid >> 4;
            const int kk = tid & 15;
            #pragma unroll
            for (int it = 0; it < 4; ++it) {
                const int rr = r + it * 16;
                As[kk][rr] = ho[(size_t)(row0 + rr) * DM + k0 + kk];
            }
        }
        {
            const int kb = tid >> 6;
            const int n  = tid & 63;
            #pragma unroll
            for (int it = 0; it < 4; ++it) {
                const int kr = kb + it * 4;
                Bs[kr][n] = wo[(size_t)(k0 + kr) * DM + col0 + n];
            }
        }
        __syncthreads();
        #pragma unroll
        for (int kk = 0; kk < 16; ++kk) {
            float a[4], b[4];
            #pragma unroll
            for (int i = 0; i < 4; ++i) a[i] = As[kk][ty * 4 + i];
            #pragma unroll
            for (int j = 0; j < 4; ++j) b[j] = Bs[kk][tx * 4 + j];
            #pragma unroll
            for (int i = 0; i < 4; ++i)
                #pragma unroll
                for (int j = 0; j < 4; ++j)
                    c[i][j] += a[i] * b[j];
        }
        __syncthreads();
    }

    #pragma unroll
    for (int i = 0; i < 4; ++i) {
        const int m = row0 + ty * 4 + i;
        #pragma unroll
        for (int j = 0; j < 4; ++j) {
            const int n = col0 + tx * 4 + j;
            out[(size_t)m * DM + n] = c[i][j] + bo[n];
        }
    }
}

// ---------------------------------------------------------------------------
extern "C" void kernel_launch(void* const* d_in, const int* in_sizes, int n_in,
                              void* d_out, int out_size, void* d_ws, size_t ws_size,
                              hipStream_t stream) {
    const float* x  = (const float*)d_in[0];
    const float* wq = (const float*)d_in[1];
    const float* bq = (const float*)d_in[2];
    const float* wk = (const float*)d_in[3];
    const float* bk = (const float*)d_in[4];
    const float* wv = (const float*)d_in[5];
    const float* bv = (const float*)d_in[6];
    const float* wo = (const float*)d_in[7];
    const float* bo = (const float*)d_in[8];

    float* out  = (float*)d_out;                             // (B,S,D) fp32
    float* attn = out + (size_t)MROWS * DM;                  // (B,H,S,S) fp32

    float* ws  = (float*)d_ws;
    float* qkv = ws;                                         // 3 * 4194304 fp32 (q,k,v)
    float* ho  = ws + 3ull * MROWS * DM;                     // 4194304 fp32

    // QKV projections + RoPE
    k_qkv<<<dim3(DM / 64, MROWS / 64, 3), dim3(16, 16), 0, stream>>>(
        x, wq, bq, wk, bk, wv, bv, qkv);

    // Attention (scores, softmax, attn materialization, PV)
    k_attn<<<dim3(SEQ / 4, NH, 2), 256, 0, stream>>>(qkv, attn, ho);

    // Output projection
    k_oproj<<<dim3(DM / 64, MROWS / 64), dim3(16, 16), 0, stream>>>(ho, wo, bo, out);
}